// Round 14
// baseline (333.811 us; speedup 1.0000x reference)
//
#include <hip/hip_runtime.h>
#include <stdint.h>

#define D_DIM  1024
#define NROWS  4096
#define NSEG   8
#define QN     4000
#define NCODES 32000
#define VOFF   2

#define LDK 40           // fallback kernel LDS pad

#define MARGIN_BF 2.0f   // fallback (bf16) margin
#define MARGIN_I8 6.0f   // i8 approx margin (~5.4 sigma of pairwise dist error)
#define CAP      262144u

// ws layout (bytes)
#define C2_OFF     0u
#define X2_OFF     131072u
#define CELLS_OFF  147456u
#define MINF_OFF   409600u
#define CNT_OFF    540672u
#define PART_OFF   540928u
#define LIST_OFF   573696u
#define STASH_OFF  1622272u
#define WS_NEED_A  10010880u
// i8 fast path buffers
#define XI8_OFF    10010880u
#define CI8_OFF    14205184u
#define SX_OFF     46973184u
#define SC_OFF     46989568u
#define WS_NEED_FAST 83935488u

typedef short bf16x8 __attribute__((ext_vector_type(8)));
typedef float f32x4  __attribute__((ext_vector_type(4)));
typedef int   i32x4  __attribute__((ext_vector_type(4)));

#define AS1(p) ((const __attribute__((address_space(1))) void*)(p))
#define AS3(p) ((__attribute__((address_space(3))) void*)(p))

__device__ inline unsigned short f2bs(float f) {   // fp32 -> bf16 RNE
  unsigned u = __float_as_uint(f);
  unsigned r = (u + 0x7FFFu + ((u >> 16) & 1u)) >> 16;
  return (unsigned short)r;
}
__device__ inline unsigned shflx_u32(unsigned v, int m) {
  return (unsigned)__shfl_xor((int)v, m, 64);
}
// float-bits candidate key: dist >= 0 so uint order == value order.
__device__ inline unsigned packkey(float d, int qloc) {
  return (__float_as_uint(fmaxf(d, 0.0f)) & 0xFFFFFF80u) | (unsigned)qloc;
}

// ---------------- rowsq: c2 / x2 (fallback paths) ----------------
__global__ __launch_bounds__(256) void rowsq_kernel(const float* __restrict__ emb,
                                                    const float* __restrict__ x,
                                                    float* __restrict__ c2,
                                                    float* __restrict__ x2) {
  int b = blockIdx.x;
  int t = threadIdx.x;
  const float* src = (b < NCODES) ? (emb + (size_t)(VOFF + b) * D_DIM)
                                  : (x + (size_t)(b - NCODES) * D_DIM);
  float4 v = ((const float4*)src)[t];
  float s = v.x * v.x + v.y * v.y + v.z * v.z + v.w * v.w;
  for (int off = 32; off > 0; off >>= 1) s += __shfl_down(s, off, 64);
  __shared__ float red[4];
  if ((t & 63) == 0) red[t >> 6] = s;
  __syncthreads();
  if (t == 0) {
    float tot = red[0] + red[1] + red[2] + red[3];
    if (b < NCODES) c2[b] = tot; else x2[b - NCODES] = tot;
  }
}

// ---------------- convert: fp32 -> per-row-scaled int8 + c2/x2 + scales ----------------
__global__ __launch_bounds__(256) void convert_i8_kernel(const float* __restrict__ emb,
                                                         const float* __restrict__ x,
                                                         char* __restrict__ ci8,
                                                         char* __restrict__ xi8,
                                                         float* __restrict__ c2,
                                                         float* __restrict__ x2,
                                                         float* __restrict__ scs,
                                                         float* __restrict__ sxs) {
  int b = blockIdx.x;
  int t = threadIdx.x;
  const float* src;
  char* dst;
  if (b < NCODES) { src = emb + (size_t)(VOFF + b) * D_DIM; dst = ci8 + (size_t)b * D_DIM; }
  else            { src = x + (size_t)(b - NCODES) * D_DIM; dst = xi8 + (size_t)(b - NCODES) * D_DIM; }
  float4 v = ((const float4*)src)[t];
  float s = v.x * v.x + v.y * v.y + v.z * v.z + v.w * v.w;
  float a = fmaxf(fmaxf(fabsf(v.x), fabsf(v.y)), fmaxf(fabsf(v.z), fabsf(v.w)));
  for (int off = 32; off > 0; off >>= 1) {
    s += __shfl_down(s, off, 64);
    a = fmaxf(a, __shfl_down(a, off, 64));
  }
  __shared__ float redS[4], redA[4];
  if ((t & 63) == 0) { redS[t >> 6] = s; redA[t >> 6] = a; }
  __syncthreads();
  float amax = fmaxf(fmaxf(redA[0], redA[1]), fmaxf(redA[2], redA[3]));
  float inv = (amax > 0.0f) ? (127.0f / amax) : 0.0f;
  char4 o;
  o.x = (char)__float2int_rn(v.x * inv);
  o.y = (char)__float2int_rn(v.y * inv);
  o.z = (char)__float2int_rn(v.z * inv);
  o.w = (char)__float2int_rn(v.w * inv);
  ((char4*)dst)[t] = o;
  if (t == 0) {
    float tot = redS[0] + redS[1] + redS[2] + redS[3];
    float scale = amax * (1.0f / 127.0f);
    if (b < NCODES) { c2[b] = tot; scs[b] = scale; }
    else            { x2[b - NCODES] = tot; sxs[b - NCODES] = scale; }
  }
}

// ---------------- FAST int8 MFMA distance GEMM (128^2, round-10 skeleton) ----------------
// i8 K=64 MFMA consumes exactly one 64B row -> byte-identical layout to the
// round-10 bf16 BK=32 kernel (64B rows, 4x16B chunks, (row>>1)&3 swizzle, same
// staging map, 3-buffer vmcnt(4) + lgkm0-before-barrier protocol). 16 K-tiles.
// LDS = 48KB -> ~3 blocks/CU co-resident: independent blocks dephase and hide
// each other's drains (m114 mechanism) -- fixes round-13's 1-block lockstep.
// Epilogue: round-10's mbuf merge (on lA[1], dead since t=13; __syncthreads
// after the loop), i8 scaled distance, float-bits stash key.
__global__ __launch_bounds__(256) void score_i8_kernel(
    const char* __restrict__ xi8, const char* __restrict__ ci8,
    const float* __restrict__ c2, const float* __restrict__ x2,
    const float* __restrict__ scs, const float* __restrict__ sxs,
    unsigned* __restrict__ stash) {
  __shared__ char lA[3][128][64];   // 24KB
  __shared__ char lB[3][128][64];   // 24KB
  int tid = threadIdx.x;

  int bid = ((blockIdx.x & 7) << 10) | (blockIdx.x >> 3);   // T1 (8192 = 8*1024)
  int lb  = bid & 63;
  int sb  = bid >> 6;
  int smx = sb & 3;
  int sqy = (sb >> 2) & 3;
  int seg = sb >> 4;             // == XCD index under round-robin dispatch
  int mx  = smx * 8 + (lb & 7);
  int qy  = sqy * 8 + (lb >> 3);
  int m0 = mx * 128, q0 = qy * 128;

  int lane = tid & 63, wid = tid >> 6;
  int wr = wid >> 1, wc = wid & 1;
  int lrow = lane & 15, kg = lane >> 4;
  const int co = ((kg ^ ((lrow >> 1) & 3)) << 4);   // swizzled read byte-col

  // staging: thread t covers physical (row t>>2, chunk t&3); fetch logical chunk ^ s(row)
  int srow = tid >> 2;
  int scol = (((tid & 3) ^ ((tid >> 3) & 3)) << 4);
  const char* aSrc0 = xi8 + (size_t)(m0 + srow) * D_DIM + scol;
  const char* aSrc1 = aSrc0 + (size_t)64 * D_DIM;
  int qb0 = q0 + srow;      if (qb0 > QN - 1) qb0 = QN - 1;
  int qb1 = q0 + srow + 64; if (qb1 > QN - 1) qb1 = QN - 1;
  const char* bSrc0 = ci8 + (size_t)(seg * QN + qb0) * D_DIM + scol;
  const char* bSrc1 = ci8 + (size_t)(seg * QN + qb1) * D_DIM + scol;
  int ldsOff = tid << 4;   // linear physical byte dest

  i32x4 acc[4][4];
#pragma unroll
  for (int i = 0; i < 4; i++)
#pragma unroll
    for (int j = 0; j < 4; j++) acc[i][j] = (i32x4){0, 0, 0, 0};

#define STAGE_F(bb, kt) {                                                            \
    __builtin_amdgcn_global_load_lds(AS1(aSrc0 + (kt)), AS3(&lA[bb][0][0]  + ldsOff), 16, 0, 0); \
    __builtin_amdgcn_global_load_lds(AS1(aSrc1 + (kt)), AS3(&lA[bb][64][0] + ldsOff), 16, 0, 0); \
    __builtin_amdgcn_global_load_lds(AS1(bSrc0 + (kt)), AS3(&lB[bb][0][0]  + ldsOff), 16, 0, 0); \
    __builtin_amdgcn_global_load_lds(AS1(bSrc1 + (kt)), AS3(&lB[bb][64][0] + ldsOff), 16, 0, 0); }

#define COMPUTE_F(bb) {                                                            \
    i32x4 af0 = *(const i32x4*)&lA[bb][wr * 64 +  0 + lrow][co];                   \
    i32x4 af1 = *(const i32x4*)&lA[bb][wr * 64 + 16 + lrow][co];                   \
    i32x4 af2 = *(const i32x4*)&lA[bb][wr * 64 + 32 + lrow][co];                   \
    i32x4 af3 = *(const i32x4*)&lA[bb][wr * 64 + 48 + lrow][co];                   \
    i32x4 bg0 = *(const i32x4*)&lB[bb][wc * 64 +  0 + lrow][co];                   \
    i32x4 bg1 = *(const i32x4*)&lB[bb][wc * 64 + 16 + lrow][co];                   \
    i32x4 bg2 = *(const i32x4*)&lB[bb][wc * 64 + 32 + lrow][co];                   \
    i32x4 bg3 = *(const i32x4*)&lB[bb][wc * 64 + 48 + lrow][co];                   \
    __builtin_amdgcn_s_setprio(1);                                                 \
    acc[0][0] = __builtin_amdgcn_mfma_i32_16x16x64_i8(af0, bg0, acc[0][0],0,0,0);  \
    acc[0][1] = __builtin_amdgcn_mfma_i32_16x16x64_i8(af0, bg1, acc[0][1],0,0,0);  \
    acc[0][2] = __builtin_amdgcn_mfma_i32_16x16x64_i8(af0, bg2, acc[0][2],0,0,0);  \
    acc[0][3] = __builtin_amdgcn_mfma_i32_16x16x64_i8(af0, bg3, acc[0][3],0,0,0);  \
    acc[1][0] = __builtin_amdgcn_mfma_i32_16x16x64_i8(af1, bg0, acc[1][0],0,0,0);  \
    acc[1][1] = __builtin_amdgcn_mfma_i32_16x16x64_i8(af1, bg1, acc[1][1],0,0,0);  \
    acc[1][2] = __builtin_amdgcn_mfma_i32_16x16x64_i8(af1, bg2, acc[1][2],0,0,0);  \
    acc[1][3] = __builtin_amdgcn_mfma_i32_16x16x64_i8(af1, bg3, acc[1][3],0,0,0);  \
    acc[2][0] = __builtin_amdgcn_mfma_i32_16x16x64_i8(af2, bg0, acc[2][0],0,0,0);  \
    acc[2][1] = __builtin_amdgcn_mfma_i32_16x16x64_i8(af2, bg1, acc[2][1],0,0,0);  \
    acc[2][2] = __builtin_amdgcn_mfma_i32_16x16x64_i8(af2, bg2, acc[2][2],0,0,0);  \
    acc[2][3] = __builtin_amdgcn_mfma_i32_16x16x64_i8(af2, bg3, acc[2][3],0,0,0);  \
    acc[3][0] = __builtin_amdgcn_mfma_i32_16x16x64_i8(af3, bg0, acc[3][0],0,0,0);  \
    acc[3][1] = __builtin_amdgcn_mfma_i32_16x16x64_i8(af3, bg1, acc[3][1],0,0,0);  \
    acc[3][2] = __builtin_amdgcn_mfma_i32_16x16x64_i8(af3, bg2, acc[3][2],0,0,0);  \
    acc[3][3] = __builtin_amdgcn_mfma_i32_16x16x64_i8(af3, bg3, acc[3][3],0,0,0);  \
    __builtin_amdgcn_s_setprio(0); }

#define VM4   asm volatile("s_waitcnt vmcnt(4)" ::: "memory")
#define VM0   asm volatile("s_waitcnt vmcnt(0)" ::: "memory")
#define LGKM0 asm volatile("s_waitcnt lgkmcnt(0)" ::: "memory")
#define BARX  __builtin_amdgcn_s_barrier()

  STAGE_F(0, 0);
  STAGE_F(1, 64);
  for (int tt = 0; tt < 12; tt += 3) {           // t = 0..11, stage tiles 2..13
    VM4; LGKM0; BARX; STAGE_F(2, (tt + 2) * 64); COMPUTE_F(0);
    VM4; LGKM0; BARX; STAGE_F(0, (tt + 3) * 64); COMPUTE_F(1);
    VM4; LGKM0; BARX; STAGE_F(1, (tt + 4) * 64); COMPUTE_F(2);
  }
  VM4; LGKM0; BARX; STAGE_F(2, 14 * 64); COMPUTE_F(0);   // t=12
  VM4; LGKM0; BARX; STAGE_F(0, 15 * 64); COMPUTE_F(1);   // t=13 (last read of lA[1])
  VM4; LGKM0; BARX; COMPUTE_F(2);                        // t=14 (tile 15 in flight)
  VM0; LGKM0; BARX; COMPUTE_F(0);                        // t=15, full drain
  __syncthreads();   // all waves' final ds_reads drained before mbuf overlay

  unsigned* mbuf = (unsigned*)&lA[1][0][0];      // dead since t=13; 2KB used

  float c2v[4], s2c[4];
  bool  val[4];
  int   qloc[4];
#pragma unroll
  for (int nt = 0; nt < 4; nt++) {
    int ql = wc * 64 + nt * 16 + lrow;
    int q = q0 + ql;
    val[nt] = (q < QN);
    qloc[nt] = ql;
    int qc = val[nt] ? q : QN - 1;
    c2v[nt] = c2[seg * QN + qc];
    s2c[nt] = 2.0f * scs[seg * QN + qc];
  }

#pragma unroll
  for (int mt = 0; mt < 4; mt++) {
#pragma unroll
    for (int r = 0; r < 4; r++) {
      int grow = m0 + wr * 64 + mt * 16 + kg * 4 + r;
      float x2r = x2[grow];
      float sxr = sxs[grow];
      unsigned b1 = 0xFFFFFFFFu, b2 = 0xFFFFFFFFu;
#pragma unroll
      for (int nt = 0; nt < 4; nt++) {
        unsigned u = 0xFFFFFFFFu;
        if (val[nt]) {
          float d = (x2r + c2v[nt]) - sxr * s2c[nt] * (float)acc[mt][nt][r];
          u = packkey(d, qloc[nt]);
        }
        if (u < b1) { b2 = b1; b1 = u; } else if (u < b2) b2 = u;
      }
#pragma unroll
      for (int m = 1; m < 16; m <<= 1) {
        unsigned o1 = shflx_u32(b1, m), o2 = shflx_u32(b2, m);
        unsigned n1 = min(b1, o1);
        unsigned n2 = min(max(b1, o1), min(b2, o2));
        b1 = n1; b2 = n2;
      }
      if (lrow == 0) {
        int rloc = wr * 64 + mt * 16 + kg * 4 + r;
        mbuf[(rloc * 2 + wc) * 2 + 0] = b1;
        mbuf[(rloc * 2 + wc) * 2 + 1] = b2;
      }
    }
  }
  __syncthreads();
  if (tid < 128) {
    unsigned p1 = mbuf[(tid * 2 + 0) * 2 + 0];
    unsigned p2 = mbuf[(tid * 2 + 0) * 2 + 1];
    unsigned g1 = mbuf[(tid * 2 + 1) * 2 + 0];
    unsigned g2 = mbuf[(tid * 2 + 1) * 2 + 1];
    unsigned m1 = min(p1, g1);
    unsigned m2 = min(max(p1, g1), min(p2, g2));
    int grow = m0 + tid;
    size_t base = ((size_t)(grow * NSEG + seg) * 32 + qy) * 2;
    stash[base + 0] = m1;
    stash[base + 1] = m2;
  }
#undef STAGE_F
#undef COMPUTE_F
#undef VM4
#undef VM0
#undef LGKM0
#undef BARX
}

// ---------------- fallback bf16 MFMA GEMM (128-tile, round-3 core) ----------------
template<int MODE>
__global__ __launch_bounds__(256) void score_mfma_kernel(
    const float* __restrict__ x, const float* __restrict__ emb,
    const float* __restrict__ c2, const float* __restrict__ x2,
    unsigned* __restrict__ minf, unsigned* __restrict__ stash,
    unsigned* __restrict__ list, unsigned* __restrict__ cnt) {
  __shared__ short lA[2][128][LDK];
  __shared__ short lB[2][128][LDK];
  int tid = threadIdx.x;
  int m0 = blockIdx.x * 128, q0 = blockIdx.y * 128, seg = blockIdx.z;
  int lane = tid & 63, wid = tid >> 6;
  int wr = wid >> 1, wc = wid & 1;
  int lrow = lane & 15, kg = lane >> 4;

  int sr = tid >> 1;
  int kh = (tid & 1) << 4;
  const float* abase = x + (size_t)(m0 + sr) * D_DIM + kh;
  int qg = q0 + sr; if (qg > QN - 1) qg = QN - 1;
  const float* bbase = emb + (size_t)(VOFF + seg * QN + qg) * D_DIM + kh;

  f32x4 acc[4][4];
#pragma unroll
  for (int i = 0; i < 4; i++)
#pragma unroll
    for (int j = 0; j < 4; j++) acc[i][j] = (f32x4){0.f, 0.f, 0.f, 0.f};

  float4 ra0, ra1, ra2, ra3, rb0, rb1, rb2, rb3;

#define LOAD_TILE(kt) {                                          \
    const float4* ap = (const float4*)(abase + (kt));            \
    const float4* bp = (const float4*)(bbase + (kt));            \
    ra0 = ap[0]; ra1 = ap[1]; ra2 = ap[2]; ra3 = ap[3];          \
    rb0 = bp[0]; rb1 = bp[1]; rb2 = bp[2]; rb3 = bp[3]; }

#define WRITE_TILE(bb) {                                                       \
    bf16x8 p0, p1, q0v, q1v;                                                   \
    p0[0]=f2bs(ra0.x); p0[1]=f2bs(ra0.y); p0[2]=f2bs(ra0.z); p0[3]=f2bs(ra0.w);\
    p0[4]=f2bs(ra1.x); p0[5]=f2bs(ra1.y); p0[6]=f2bs(ra1.z); p0[7]=f2bs(ra1.w);\
    p1[0]=f2bs(ra2.x); p1[1]=f2bs(ra2.y); p1[2]=f2bs(ra2.z); p1[3]=f2bs(ra2.w);\
    p1[4]=f2bs(ra3.x); p1[5]=f2bs(ra3.y); p1[6]=f2bs(ra3.z); p1[7]=f2bs(ra3.w);\
    q0v[0]=f2bs(rb0.x); q0v[1]=f2bs(rb0.y); q0v[2]=f2bs(rb0.z); q0v[3]=f2bs(rb0.w);\
    q0v[4]=f2bs(rb1.x); q0v[5]=f2bs(rb1.y); q0v[6]=f2bs(rb1.z); q0v[7]=f2bs(rb1.w);\
    q1v[0]=f2bs(rb2.x); q1v[1]=f2bs(rb2.y); q1v[2]=f2bs(rb2.z); q1v[3]=f2bs(rb2.w);\
    q1v[4]=f2bs(rb3.x); q1v[5]=f2bs(rb3.y); q1v[6]=f2bs(rb3.z); q1v[7]=f2bs(rb3.w);\
    *(bf16x8*)&lA[bb][sr][kh]     = p0;  *(bf16x8*)&lA[bb][sr][kh + 8] = p1;   \
    *(bf16x8*)&lB[bb][sr][kh]     = q0v; *(bf16x8*)&lB[bb][sr][kh + 8] = q1v; }

#define COMPUTE(bb) {                                                              \
    bf16x8 af0 = *(const bf16x8*)&lA[bb][wr * 64 +  0 + lrow][kg * 8];             \
    bf16x8 af1 = *(const bf16x8*)&lA[bb][wr * 64 + 16 + lrow][kg * 8];             \
    bf16x8 af2 = *(const bf16x8*)&lA[bb][wr * 64 + 32 + lrow][kg * 8];             \
    bf16x8 af3 = *(const bf16x8*)&lA[bb][wr * 64 + 48 + lrow][kg * 8];             \
    bf16x8 bg0 = *(const bf16x8*)&lB[bb][wc * 64 +  0 + lrow][kg * 8];             \
    bf16x8 bg1 = *(const bf16x8*)&lB[bb][wc * 64 + 16 + lrow][kg * 8];             \
    bf16x8 bg2 = *(const bf16x8*)&lB[bb][wc * 64 + 32 + lrow][kg * 8];             \
    bf16x8 bg3 = *(const bf16x8*)&lB[bb][wc * 64 + 48 + lrow][kg * 8];             \
    acc[0][0] = __builtin_amdgcn_mfma_f32_16x16x32_bf16(af0, bg0, acc[0][0],0,0,0);\
    acc[0][1] = __builtin_amdgcn_mfma_f32_16x16x32_bf16(af0, bg1, acc[0][1],0,0,0);\
    acc[0][2] = __builtin_amdgcn_mfma_f32_16x16x32_bf16(af0, bg2, acc[0][2],0,0,0);\
    acc[0][3] = __builtin_amdgcn_mfma_f32_16x16x32_bf16(af0, bg3, acc[0][3],0,0,0);\
    acc[1][0] = __builtin_amdgcn_mfma_f32_16x16x32_bf16(af1, bg0, acc[1][0],0,0,0);\
    acc[1][1] = __builtin_amdgcn_mfma_f32_16x16x32_bf16(af1, bg1, acc[1][1],0,0,0);\
    acc[1][2] = __builtin_amdgcn_mfma_f32_16x16x32_bf16(af1, bg2, acc[1][2],0,0,0);\
    acc[1][3] = __builtin_amdgcn_mfma_f32_16x16x32_bf16(af1, bg3, acc[1][3],0,0,0);\
    acc[2][0] = __builtin_amdgcn_mfma_f32_16x16x32_bf16(af2, bg0, acc[2][0],0,0,0);\
    acc[2][1] = __builtin_amdgcn_mfma_f32_16x16x32_bf16(af2, bg1, acc[2][1],0,0,0);\
    acc[2][2] = __builtin_amdgcn_mfma_f32_16x16x32_bf16(af2, bg2, acc[2][2],0,0,0);\
    acc[2][3] = __builtin_amdgcn_mfma_f32_16x16x32_bf16(af2, bg3, acc[2][3],0,0,0);\
    acc[3][0] = __builtin_amdgcn_mfma_f32_16x16x32_bf16(af3, bg0, acc[3][0],0,0,0);\
    acc[3][1] = __builtin_amdgcn_mfma_f32_16x16x32_bf16(af3, bg1, acc[3][1],0,0,0);\
    acc[3][2] = __builtin_amdgcn_mfma_f32_16x16x32_bf16(af3, bg2, acc[3][2],0,0,0);\
    acc[3][3] = __builtin_amdgcn_mfma_f32_16x16x32_bf16(af3, bg3, acc[3][3],0,0,0); }

  LOAD_TILE(0);
  WRITE_TILE(0);
  __syncthreads();
  int buf = 0;
  for (int kt = 32; kt < D_DIM; kt += 32) {
    LOAD_TILE(kt);
    COMPUTE(buf);
    WRITE_TILE(buf ^ 1);
    __syncthreads();
    buf ^= 1;
  }
  COMPUTE(buf);
  unsigned* mbuf = (unsigned*)&lA[0][0][0];

  float c2v[4];
  bool  val[4];
  int   qloc[4];
#pragma unroll
  for (int nt = 0; nt < 4; nt++) {
    int ql = wc * 64 + nt * 16 + lrow;
    int q = q0 + ql;
    val[nt] = (q < QN);
    qloc[nt] = ql;
    c2v[nt] = c2[seg * QN + (val[nt] ? q : QN - 1)];
  }

#pragma unroll
  for (int mt = 0; mt < 4; mt++) {
#pragma unroll
    for (int r = 0; r < 4; r++) {
      int grow = m0 + wr * 64 + mt * 16 + kg * 4 + r;
      float x2r = x2[grow];
      if constexpr (MODE == 0) {
        float dmin = 1e30f;
#pragma unroll
        for (int nt = 0; nt < 4; nt++) {
          if (val[nt]) {
            float d = (x2r + c2v[nt]) - 2.0f * acc[mt][nt][r];
            dmin = fminf(dmin, d);
          }
        }
        dmin = fminf(dmin, __shfl_xor(dmin, 1, 64));
        dmin = fminf(dmin, __shfl_xor(dmin, 2, 64));
        dmin = fminf(dmin, __shfl_xor(dmin, 4, 64));
        dmin = fminf(dmin, __shfl_xor(dmin, 8, 64));
        if (lrow == 0)
          atomicMin(&minf[grow * NSEG + seg], __float_as_uint(fmaxf(dmin, 0.0f)));
      } else if constexpr (MODE == 1) {
        unsigned b1 = 0xFFFFFFFFu, b2 = 0xFFFFFFFFu;
#pragma unroll
        for (int nt = 0; nt < 4; nt++) {
          unsigned u = 0xFFFFFFFFu;
          if (val[nt]) {
            float d = (x2r + c2v[nt]) - 2.0f * acc[mt][nt][r];
            u = packkey(d, qloc[nt]);
          }
          if (u < b1) { b2 = b1; b1 = u; } else if (u < b2) b2 = u;
        }
#pragma unroll
        for (int m = 1; m < 16; m <<= 1) {
          unsigned o1 = shflx_u32(b1, m), o2 = shflx_u32(b2, m);
          unsigned n1 = min(b1, o1);
          unsigned n2 = min(max(b1, o1), min(b2, o2));
          b1 = n1; b2 = n2;
        }
        if (lrow == 0) {
          int rloc = wr * 64 + mt * 16 + kg * 4 + r;
          mbuf[(rloc * 2 + wc) * 2 + 0] = b1;
          mbuf[(rloc * 2 + wc) * 2 + 1] = b2;
        }
      } else {
        float dm = __uint_as_float(minf[grow * NSEG + seg]) + MARGIN_BF;
#pragma unroll
        for (int nt = 0; nt < 4; nt++) {
          if (val[nt]) {
            float d = (x2r + c2v[nt]) - 2.0f * acc[mt][nt][r];
            if (d <= dm) {
              unsigned idx = atomicAdd(cnt, 1u);
              if (idx < CAP)
                list[idx] = ((unsigned)grow << 15) | ((unsigned)seg << 12) |
                            (unsigned)(q0 + qloc[nt]);
            }
          }
        }
      }
    }
  }

  if constexpr (MODE == 1) {
    __syncthreads();
    if (tid < 128) {
      unsigned p1 = mbuf[(tid * 2 + 0) * 2 + 0];
      unsigned p2 = mbuf[(tid * 2 + 0) * 2 + 1];
      unsigned g1 = mbuf[(tid * 2 + 1) * 2 + 0];
      unsigned g2 = mbuf[(tid * 2 + 1) * 2 + 1];
      unsigned m1 = min(p1, g1);
      unsigned m2 = min(max(p1, g1), min(p2, g2));
      int grow = m0 + tid;
      size_t base = ((size_t)(grow * NSEG + seg) * 32 + blockIdx.y) * 2;
      stash[base + 0] = m1;
      stash[base + 1] = m2;
    }
  }
#undef LOAD_TILE
#undef WRITE_TILE
#undef COMPUTE
}

// ---------------- fused filter + exact fp32 rescore (one wave per cell) ----------------
__global__ __launch_bounds__(256) void filter_rescore_kernel(
    const float* __restrict__ x, const float* __restrict__ emb,
    const float* __restrict__ c2, const float* __restrict__ x2,
    const unsigned* __restrict__ stash, unsigned long long* __restrict__ cells,
    float margin) {
  int cell = blockIdx.x * 4 + (threadIdx.x >> 6);   // 32768 cells
  int lane = threadIdx.x & 63;
  int row = cell >> 3, seg = cell & 7;
  unsigned e = stash[(size_t)cell * 64 + lane];
  unsigned m = e;
  for (int msk = 1; msk < 64; msk <<= 1) m = min(m, shflx_u32(m, msk));
  float dcut = __uint_as_float(m & 0xFFFFFF80u) + margin;
  int myq = ((lane >> 1) << 7) + (int)(e & 127u);
  bool qual = (e != 0xFFFFFFFFu) &&
              (__uint_as_float(e & 0xFFFFFF80u) <= dcut) && (myq < QN);
  unsigned long long mask = __ballot(qual);
  unsigned long long best = 0ULL;
  const float4* xr = (const float4*)(x + (size_t)row * D_DIM);
  float x2r = x2[row];
  while (mask) {
    int L = __ffsll((long long)mask) - 1;
    mask &= mask - 1;
    int q = __shfl(myq, L, 64);
    const float4* cr = (const float4*)(emb + (size_t)(VOFF + seg * QN + q) * D_DIM);
    float s = 0.f;
#pragma unroll
    for (int j = 0; j < 4; j++) {
      float4 a = xr[j * 64 + lane];
      float4 b = cr[j * 64 + lane];
      s += a.x * b.x + a.y * b.y + a.z * b.z + a.w * b.w;
    }
    for (int msk2 = 1; msk2 < 64; msk2 <<= 1) s += __shfl_xor(s, msk2, 64);
    float dist = (x2r + c2[seg * QN + q]) - 2.0f * s;
    unsigned u = __float_as_uint(dist);
    unsigned asc = (u & 0x80000000u) ? ~u : (u | 0x80000000u);
    unsigned long long p = ((unsigned long long)(~asc) << 32) |
                           (unsigned long long)(~(unsigned)q);
    if (p > best) best = p;
  }
  if (lane == 0) cells[(size_t)row * NSEG + seg] = best;
}

// ---------------- list-based rescore (fallback path B only) ----------------
__global__ __launch_bounds__(256) void rescore_kernel(const float* __restrict__ x,
                                                      const float* __restrict__ emb,
                                                      const float* __restrict__ c2,
                                                      const float* __restrict__ x2,
                                                      const unsigned* __restrict__ list,
                                                      const unsigned* __restrict__ cnt,
                                                      unsigned long long* __restrict__ cells) {
  int nw = gridDim.x * 4;
  int wv = blockIdx.x * 4 + (threadIdx.x >> 6);
  int lane = threadIdx.x & 63;
  unsigned n = *cnt; if (n > CAP) n = CAP;
  for (unsigned i = wv; i < n; i += nw) {
    unsigned e = list[i];
    int row = e >> 15, seg = (e >> 12) & 7, q = e & 4095;
    const float4* xr = (const float4*)(x + (size_t)row * D_DIM);
    const float4* cr = (const float4*)(emb + (size_t)(VOFF + seg * QN + q) * D_DIM);
    float s = 0.f;
#pragma unroll
    for (int j = 0; j < 4; j++) {
      float4 a = xr[j * 64 + lane];
      float4 b = cr[j * 64 + lane];
      s += a.x * b.x + a.y * b.y + a.z * b.z + a.w * b.w;
    }
    for (int msk = 1; msk < 64; msk <<= 1) s += __shfl_xor(s, msk, 64);
    float dist = (x2[row] + c2[seg * QN + q]) - 2.0f * s;
    unsigned u = __float_as_uint(dist);
    unsigned asc = (u & 0x80000000u) ? ~u : (u | 0x80000000u);
    unsigned long long p = ((unsigned long long)(~asc) << 32) |
                           (unsigned long long)(~(unsigned)q);
    if (lane == 0) atomicMax(&cells[(size_t)row * NSEG + seg], p);
  }
}

// ---------------- gather + mse partial (fp32 emb) ----------------
__global__ __launch_bounds__(256) void gather_kernel(const float* __restrict__ x,
                                                     const float* __restrict__ emb,
                                                     const float* __restrict__ mask,
                                                     const unsigned long long* __restrict__ cells,
                                                     float* __restrict__ out,
                                                     double* __restrict__ part) {
  int n = blockIdx.x;
  int t = threadIdx.x;
  __shared__ int qsel[NSEG];
  if (t < NSEG) qsel[t] = (int)(~(unsigned)(cells[(size_t)n * NSEG + t] & 0xffffffffULL));
  __syncthreads();
  float4 xv = ((const float4*)(x + (size_t)n * D_DIM))[t];
  float ax = 0.f, ay = 0.f, az = 0.f, aw = 0.f;
#pragma unroll
  for (int s = 0; s < NSEG; s++) {
    float4 cv = ((const float4*)(emb + (size_t)(VOFF + s * QN + qsel[s]) * D_DIM))[t];
    ax += cv.x; ay += cv.y; az += cv.z; aw += cv.w;
  }
  float qx = ax * 0.125f, qy = ay * 0.125f, qz = az * 0.125f, qw = aw * 0.125f;
  float4 o4;
  o4.x = xv.x + (qx - xv.x);
  o4.y = xv.y + (qy - xv.y);
  o4.z = xv.z + (qz - xv.z);
  o4.w = xv.w + (qw - xv.w);
  ((float4*)(out + (size_t)n * D_DIM))[t] = o4;
  float mk = mask[n];
  float dx = qx * mk - xv.x * mk;
  float dy = qy * mk - xv.y * mk;
  float dz = qz * mk - xv.z * mk;
  float dw = qw * mk - xv.w * mk;
  float ss = dx * dx + dy * dy + dz * dz + dw * dw;
  double sd = (double)ss;
  for (int off = 32; off > 0; off >>= 1) sd += __shfl_down(sd, off, 64);
  __shared__ double red[4];
  if ((t & 63) == 0) red[t >> 6] = sd;
  __syncthreads();
  if (t == 0) part[n] = red[0] + red[1] + red[2] + red[3];
}

__global__ __launch_bounds__(256) void finalize_kernel(const double* __restrict__ part,
                                                       float* __restrict__ loss_out) {
  int t = threadIdx.x;
  double s = 0.0;
  for (int i = t; i < NROWS; i += 256) s += part[i];
  for (int off = 32; off > 0; off >>= 1) s += __shfl_down(s, off, 64);
  __shared__ double red[4];
  if ((t & 63) == 0) red[t >> 6] = s;
  __syncthreads();
  if (t == 0) {
    double tot = red[0] + red[1] + red[2] + red[3];
    float m = (float)(tot / (double)((size_t)NROWS * D_DIM));
    loss_out[0] = m + 0.25f * m;
  }
}

extern "C" void kernel_launch(void* const* d_in, const int* in_sizes, int n_in,
                              void* d_out, int out_size, void* d_ws, size_t ws_size,
                              hipStream_t stream) {
  const float* x    = (const float*)d_in[0];
  const float* emb  = (const float*)d_in[1];
  const float* mask = (const float*)d_in[2];
  (void)in_sizes; (void)n_in; (void)out_size;

  char* ws = (char*)d_ws;
  float* c2 = (float*)(ws + C2_OFF);
  float* x2 = (float*)(ws + X2_OFF);
  unsigned long long* cells = (unsigned long long*)(ws + CELLS_OFF);
  unsigned* minf = (unsigned*)(ws + MINF_OFF);
  unsigned* cnt  = (unsigned*)(ws + CNT_OFF);
  double*   part = (double*)(ws + PART_OFF);
  unsigned* list = (unsigned*)(ws + LIST_OFF);
  unsigned* stash = (unsigned*)(ws + STASH_OFF);
  char* xi8 = ws + XI8_OFF;
  char* ci8 = ws + CI8_OFF;
  float* sxs = (float*)(ws + SX_OFF);
  float* scs = (float*)(ws + SC_OFF);
  float* out = (float*)d_out;

  hipMemsetAsync(cells, 0, 262144, stream);
  hipMemsetAsync(cnt, 0, 256, stream);

  if (ws_size >= (size_t)WS_NEED_FAST) {
    convert_i8_kernel<<<dim3(NCODES + NROWS), 256, 0, stream>>>(emb, x, ci8, xi8, c2, x2, scs, sxs);
    score_i8_kernel<<<dim3(8192), 256, 0, stream>>>(xi8, ci8, c2, x2, scs, sxs, stash);
    filter_rescore_kernel<<<dim3(8192), 256, 0, stream>>>(x, emb, c2, x2, stash, cells, MARGIN_I8);
    gather_kernel<<<dim3(NROWS), 256, 0, stream>>>(x, emb, mask, cells, out, part);
  } else if (ws_size >= (size_t)WS_NEED_A) {
    rowsq_kernel<<<dim3(NCODES + NROWS), 256, 0, stream>>>(emb, x, c2, x2);
    score_mfma_kernel<1><<<dim3(NROWS / 128, (QN + 127) / 128, NSEG), 256, 0, stream>>>(
        x, emb, c2, x2, minf, stash, list, cnt);
    filter_rescore_kernel<<<dim3(8192), 256, 0, stream>>>(x, emb, c2, x2, stash, cells, MARGIN_BF);
    gather_kernel<<<dim3(NROWS), 256, 0, stream>>>(x, emb, mask, cells, out, part);
  } else {
    hipMemsetAsync(minf, 0xFF, 131072, stream);
    rowsq_kernel<<<dim3(NCODES + NROWS), 256, 0, stream>>>(emb, x, c2, x2);
    score_mfma_kernel<0><<<dim3(NROWS / 128, (QN + 127) / 128, NSEG), 256, 0, stream>>>(
        x, emb, c2, x2, minf, stash, list, cnt);
    score_mfma_kernel<2><<<dim3(NROWS / 128, (QN + 127) / 128, NSEG), 256, 0, stream>>>(
        x, emb, c2, x2, minf, stash, list, cnt);
    rescore_kernel<<<dim3(2048), 256, 0, stream>>>(x, emb, c2, x2, list, cnt, cells);
    gather_kernel<<<dim3(NROWS), 256, 0, stream>>>(x, emb, mask, cells, out, part);
  }
  finalize_kernel<<<dim3(1), 256, 0, stream>>>(part, out + (size_t)NROWS * D_DIM);
}

// Round 15
// 282.498 us; speedup vs baseline: 1.1816x; 1.1816x over previous
//
#include <hip/hip_runtime.h>
#include <stdint.h>

#define D_DIM  1024
#define NROWS  4096
#define NSEG   8
#define QN     4000
#define NCODES 32000
#define VOFF   2

#define BM 256
#define BN 256
#define BKI 128          // i8 K-tile (128 elements = 128 B/row)
#define LDK 40           // fallback kernel LDS pad

#define MARGIN_BF 2.0f   // fallback (bf16) margin
#define MARGIN_I8 6.0f   // i8 approx margin (~5.4 sigma of pairwise dist error)
#define CAP      262144u

// ws layout (bytes)
#define C2_OFF     0u
#define X2_OFF     131072u
#define CELLS_OFF  147456u
#define MINF_OFF   409600u
#define CNT_OFF    540672u
#define PART_OFF   540928u
#define LIST_OFF   573696u
#define STASH_OFF  1622272u
#define WS_NEED_A  10010880u
// i8 fast path buffers
#define XI8_OFF    10010880u
#define CI8_OFF    14205184u
#define SX_OFF     46973184u
#define SC_OFF     46989568u
#define WS_NEED_FAST 83935488u

typedef short bf16x8 __attribute__((ext_vector_type(8)));
typedef float f32x4  __attribute__((ext_vector_type(4)));
typedef int   i32x4  __attribute__((ext_vector_type(4)));

#define AS1(p) ((const __attribute__((address_space(1))) void*)(p))
#define AS3(p) ((__attribute__((address_space(3))) void*)(p))

__device__ inline unsigned short f2bs(float f) {   // fp32 -> bf16 RNE
  unsigned u = __float_as_uint(f);
  unsigned r = (u + 0x7FFFu + ((u >> 16) & 1u)) >> 16;
  return (unsigned short)r;
}
__device__ inline unsigned shflx_u32(unsigned v, int m) {
  return (unsigned)__shfl_xor((int)v, m, 64);
}
// float-bits candidate key: dist >= 0 so uint order == value order.
__device__ inline unsigned packkey(float d, int qloc) {
  return (__float_as_uint(fmaxf(d, 0.0f)) & 0xFFFFFF80u) | (unsigned)qloc;
}

// ---------------- rowsq: c2 / x2 (fallback paths) ----------------
__global__ __launch_bounds__(256) void rowsq_kernel(const float* __restrict__ emb,
                                                    const float* __restrict__ x,
                                                    float* __restrict__ c2,
                                                    float* __restrict__ x2) {
  int b = blockIdx.x;
  int t = threadIdx.x;
  const float* src = (b < NCODES) ? (emb + (size_t)(VOFF + b) * D_DIM)
                                  : (x + (size_t)(b - NCODES) * D_DIM);
  float4 v = ((const float4*)src)[t];
  float s = v.x * v.x + v.y * v.y + v.z * v.z + v.w * v.w;
  for (int off = 32; off > 0; off >>= 1) s += __shfl_down(s, off, 64);
  __shared__ float red[4];
  if ((t & 63) == 0) red[t >> 6] = s;
  __syncthreads();
  if (t == 0) {
    float tot = red[0] + red[1] + red[2] + red[3];
    if (b < NCODES) c2[b] = tot; else x2[b - NCODES] = tot;
  }
}

// ---------------- convert: fp32 -> per-row-scaled int8 + c2/x2 + scales ----------------
__global__ __launch_bounds__(256) void convert_i8_kernel(const float* __restrict__ emb,
                                                         const float* __restrict__ x,
                                                         char* __restrict__ ci8,
                                                         char* __restrict__ xi8,
                                                         float* __restrict__ c2,
                                                         float* __restrict__ x2,
                                                         float* __restrict__ scs,
                                                         float* __restrict__ sxs) {
  int b = blockIdx.x;
  int t = threadIdx.x;
  const float* src;
  char* dst;
  if (b < NCODES) { src = emb + (size_t)(VOFF + b) * D_DIM; dst = ci8 + (size_t)b * D_DIM; }
  else            { src = x + (size_t)(b - NCODES) * D_DIM; dst = xi8 + (size_t)(b - NCODES) * D_DIM; }
  float4 v = ((const float4*)src)[t];
  float s = v.x * v.x + v.y * v.y + v.z * v.z + v.w * v.w;
  float a = fmaxf(fmaxf(fabsf(v.x), fabsf(v.y)), fmaxf(fabsf(v.z), fabsf(v.w)));
  for (int off = 32; off > 0; off >>= 1) {
    s += __shfl_down(s, off, 64);
    a = fmaxf(a, __shfl_down(a, off, 64));
  }
  __shared__ float redS[4], redA[4];
  if ((t & 63) == 0) { redS[t >> 6] = s; redA[t >> 6] = a; }
  __syncthreads();
  float amax = fmaxf(fmaxf(redA[0], redA[1]), fmaxf(redA[2], redA[3]));
  float inv = (amax > 0.0f) ? (127.0f / amax) : 0.0f;
  char4 o;
  o.x = (char)__float2int_rn(v.x * inv);
  o.y = (char)__float2int_rn(v.y * inv);
  o.z = (char)__float2int_rn(v.z * inv);
  o.w = (char)__float2int_rn(v.w * inv);
  ((char4*)dst)[t] = o;
  if (t == 0) {
    float tot = redS[0] + redS[1] + redS[2] + redS[3];
    float scale = amax * (1.0f / 127.0f);
    if (b < NCODES) { c2[b] = tot; scs[b] = scale; }
    else            { x2[b - NCODES] = tot; sxs[b - NCODES] = scale; }
  }
}

// ---------------- FAST int8 MFMA distance GEMM (256^2, 8-phase, BK=128) ----------------
// Round-13 kernel verbatim (best measured: 255us score, 282us total).
// Round-14's 128^2/3-block occupancy split regressed (296us): quartering the
// tile quadrupled per-tile fixed costs and occupancy never rose. 256^2 + BK=128
// + 4-quadrant phases is the measured local optimum of this decomposition.
__global__ __launch_bounds__(512, 2) void score_i8_kernel(
    const char* __restrict__ xi8, const char* __restrict__ ci8,
    const float* __restrict__ c2, const float* __restrict__ x2,
    const float* __restrict__ scs, const float* __restrict__ sxs,
    unsigned* __restrict__ stash) {
  __shared__ char lA[2][BM][BKI];   // 64KB
  __shared__ char lB[2][BN][BKI];   // 64KB
  int tid = threadIdx.x;

  // T1: bijective XCD swizzle (2048 = 8 XCD * 256); seg == XCD
  int bid = ((blockIdx.x & 7) << 8) | (blockIdx.x >> 3);
  int seg = bid >> 8;
  int lb  = bid & 255;             // 16m x 16q tiles, 4x4 L2 grouping
  int g   = lb >> 4;
  int gi  = lb & 15;
  int mx  = (g & 3) * 4 + (gi & 3);
  int qy  = (g >> 2) * 4 + (gi >> 2);
  int m0 = mx * BM, q0 = qy * BN;

  int lane = tid & 63, wid = tid >> 6;
  int wr = wid & 3, wc = wid >> 2;           // 4M x 2N: wave-tile 64 rows x 128 q
  int lrow = lane & 15, kg = lane >> 4;
  // swizzled read byte-cols for k-slice 0 / 1: chunk c = ks*4+kg, phys = c ^ (row&7)
  const int co0 = ((kg       ^ (lrow & 7)) << 4);
  const int co1 = (((4 | kg) ^ (lrow & 7)) << 4);

  // staging: thread t -> (row t>>3 within 64-row region, phys chunk t&7);
  // fetch LOGICAL chunk (t&7) ^ ((t>>3)&7) so LDS dest stays linear.
  int csh = (((tid & 7) ^ ((tid >> 3) & 7)) << 4);
  const char* aSt = xi8 + (size_t)(m0 + (tid >> 3)) * D_DIM + csh;
  const char* bSt0; const char* bSt1; const char* bSt2; const char* bSt3;
  {
    int r0 = q0 +   0 + (tid >> 3); if (r0 > QN - 1) r0 = QN - 1;
    int r1 = q0 +  64 + (tid >> 3); if (r1 > QN - 1) r1 = QN - 1;
    int r2 = q0 + 128 + (tid >> 3); if (r2 > QN - 1) r2 = QN - 1;
    int r3 = q0 + 192 + (tid >> 3); if (r3 > QN - 1) r3 = QN - 1;
    bSt0 = ci8 + (size_t)(seg * QN + r0) * D_DIM + csh;
    bSt1 = ci8 + (size_t)(seg * QN + r1) * D_DIM + csh;
    bSt2 = ci8 + (size_t)(seg * QN + r2) * D_DIM + csh;
    bSt3 = ci8 + (size_t)(seg * QN + r3) * D_DIM + csh;
  }
  int ldsOff = tid << 4;   // linear byte dest within each 64-row region

  i32x4 aR[2][2];          // A half: 2 m-frags x 2 k-slices (16B each)
  i32x4 bR[4][2];          // B half: 4 n-frags x 2 k-slices
  i32x4 acc[4][8];
#pragma unroll
  for (int i = 0; i < 4; i++)
#pragma unroll
    for (int j = 0; j < 8; j++) acc[i][j] = (i32x4){0, 0, 0, 0};

#define STAGE_A(bb, kt) {                                                                      \
    __builtin_amdgcn_global_load_lds(AS1(aSt + (size_t)  0 * D_DIM + (kt)), AS3(&lA[bb][  0][0] + ldsOff), 16, 0, 0); \
    __builtin_amdgcn_global_load_lds(AS1(aSt + (size_t) 64 * D_DIM + (kt)), AS3(&lA[bb][ 64][0] + ldsOff), 16, 0, 0); \
    __builtin_amdgcn_global_load_lds(AS1(aSt + (size_t)128 * D_DIM + (kt)), AS3(&lA[bb][128][0] + ldsOff), 16, 0, 0); \
    __builtin_amdgcn_global_load_lds(AS1(aSt + (size_t)192 * D_DIM + (kt)), AS3(&lA[bb][192][0] + ldsOff), 16, 0, 0); }
#define STAGE_B(bb, kt) {                                                                      \
    __builtin_amdgcn_global_load_lds(AS1(bSt0 + (kt)), AS3(&lB[bb][  0][0] + ldsOff), 16, 0, 0); \
    __builtin_amdgcn_global_load_lds(AS1(bSt1 + (kt)), AS3(&lB[bb][ 64][0] + ldsOff), 16, 0, 0); \
    __builtin_amdgcn_global_load_lds(AS1(bSt2 + (kt)), AS3(&lB[bb][128][0] + ldsOff), 16, 0, 0); \
    __builtin_amdgcn_global_load_lds(AS1(bSt3 + (kt)), AS3(&lB[bb][192][0] + ldsOff), 16, 0, 0); }

#define READ_A(bb, mh) { _Pragma("unroll")                                         \
    for (int i = 0; i < 2; i++) {                                                  \
      const char* pa = &lA[bb][wr * 64 + (mh) * 32 + i * 16 + lrow][0];            \
      aR[i][0] = *(const i32x4*)(pa + co0);                                        \
      aR[i][1] = *(const i32x4*)(pa + co1); } }
#define READ_B(bb, nh) { _Pragma("unroll")                                         \
    for (int j = 0; j < 4; j++) {                                                  \
      const char* pb = &lB[bb][wc * 128 + (nh) * 64 + j * 16 + lrow][0];           \
      bR[j][0] = *(const i32x4*)(pb + co0);                                        \
      bR[j][1] = *(const i32x4*)(pb + co1); } }

#define MFMA_Q(mh, nh) {                                                           \
    __builtin_amdgcn_s_setprio(1);                                                 \
    _Pragma("unroll") for (int ks = 0; ks < 2; ks++)                               \
      _Pragma("unroll") for (int i = 0; i < 2; i++)                                \
        _Pragma("unroll") for (int j = 0; j < 4; j++)                              \
          acc[(mh)*2 + i][(nh)*4 + j] = __builtin_amdgcn_mfma_i32_16x16x64_i8(     \
              aR[i][ks], bR[j][ks], acc[(mh)*2 + i][(nh)*4 + j], 0, 0, 0);         \
    __builtin_amdgcn_s_setprio(0); }

#define VM0   asm volatile("s_waitcnt vmcnt(0)" ::: "memory")
#define LGKM0 asm volatile("s_waitcnt lgkmcnt(0)" ::: "memory")
#define BARX  __builtin_amdgcn_s_barrier()

  // prologue: tile 0 fully staged
  STAGE_A(0, 0);
  STAGE_B(0, 0);
  VM0; BARX;

  int buf = 0;
  for (int t = 0; t < 8; ++t) {           // 8 K-tiles of 128 elements
    int ktn = (t + 1) << 7;
    // phase 0: quadrant (m0, n0); stage next-tile A
    READ_A(buf, 0); READ_B(buf, 0);
    if (t < 7) STAGE_A(buf ^ 1, ktn);
    BARX; LGKM0; MFMA_Q(0, 0); BARX;
    // phase 1: (m1, n0); stage next-tile B
    READ_A(buf, 1);
    if (t < 7) STAGE_B(buf ^ 1, ktn);
    BARX; LGKM0; MFMA_Q(1, 0); BARX;
    // phase 2: (m1, n1)
    READ_B(buf, 1);
    BARX; LGKM0; MFMA_Q(1, 1); BARX;
    // phase 3: (m0, n1); boundary drain (stages had phases 2-3 to land)
    READ_A(buf, 0);
    BARX; LGKM0; MFMA_Q(0, 1);
    VM0; LGKM0; BARX;
    buf ^= 1;
  }

  // ---- epilogue: wave-local exact top-2 per (row, 128-q tile) ----
  // d = x2 + c2 - 2*sx*sc*acc_int
  float c2v[8], s2c[8];
  bool  val[8];
#pragma unroll
  for (int nf = 0; nf < 8; nf++) {
    int q = q0 + wc * 128 + nf * 16 + lrow;
    val[nf] = (q < QN);
    int qc = val[nf] ? q : QN - 1;
    c2v[nf] = c2[seg * QN + qc];
    s2c[nf] = 2.0f * scs[seg * QN + qc];
  }

#pragma unroll
  for (int mf = 0; mf < 4; mf++) {
#pragma unroll
    for (int r = 0; r < 4; r++) {
      int grow = m0 + wr * 64 + mf * 16 + kg * 4 + r;
      float x2r = x2[grow];
      float sxr = sxs[grow];
      unsigned b1 = 0xFFFFFFFFu, b2 = 0xFFFFFFFFu;
#pragma unroll
      for (int nf = 0; nf < 8; nf++) {
        unsigned u = 0xFFFFFFFFu;
        if (val[nf]) {
          float d = (x2r + c2v[nf]) - sxr * s2c[nf] * (float)acc[mf][nf][r];
          u = packkey(d, nf * 16 + lrow);   // qloc within 128-tile (7 bits)
        }
        if (u < b1) { b2 = b1; b1 = u; } else if (u < b2) b2 = u;
      }
#pragma unroll
      for (int m = 1; m < 16; m <<= 1) {    // reduce over lrow (16-lane groups)
        unsigned o1 = shflx_u32(b1, m), o2 = shflx_u32(b2, m);
        unsigned n1 = min(b1, o1);
        unsigned n2 = min(max(b1, o1), min(b2, o2));
        b1 = n1; b2 = n2;
      }
      if (lrow == 0) {
        size_t base = ((size_t)(grow * NSEG + seg) * 32 + (qy * 2 + wc)) * 2;
        stash[base + 0] = b1;
        stash[base + 1] = b2;
      }
    }
  }
#undef STAGE_A
#undef STAGE_B
#undef READ_A
#undef READ_B
#undef MFMA_Q
#undef VM0
#undef LGKM0
#undef BARX
}

// ---------------- fallback bf16 MFMA GEMM (128-tile, round-3 core) ----------------
template<int MODE>
__global__ __launch_bounds__(256) void score_mfma_kernel(
    const float* __restrict__ x, const float* __restrict__ emb,
    const float* __restrict__ c2, const float* __restrict__ x2,
    unsigned* __restrict__ minf, unsigned* __restrict__ stash,
    unsigned* __restrict__ list, unsigned* __restrict__ cnt) {
  __shared__ short lA[2][128][LDK];
  __shared__ short lB[2][128][LDK];
  int tid = threadIdx.x;
  int m0 = blockIdx.x * 128, q0 = blockIdx.y * 128, seg = blockIdx.z;
  int lane = tid & 63, wid = tid >> 6;
  int wr = wid >> 1, wc = wid & 1;
  int lrow = lane & 15, kg = lane >> 4;

  int sr = tid >> 1;
  int kh = (tid & 1) << 4;
  const float* abase = x + (size_t)(m0 + sr) * D_DIM + kh;
  int qg = q0 + sr; if (qg > QN - 1) qg = QN - 1;
  const float* bbase = emb + (size_t)(VOFF + seg * QN + qg) * D_DIM + kh;

  f32x4 acc[4][4];
#pragma unroll
  for (int i = 0; i < 4; i++)
#pragma unroll
    for (int j = 0; j < 4; j++) acc[i][j] = (f32x4){0.f, 0.f, 0.f, 0.f};

  float4 ra0, ra1, ra2, ra3, rb0, rb1, rb2, rb3;

#define LOAD_TILE(kt) {                                          \
    const float4* ap = (const float4*)(abase + (kt));            \
    const float4* bp = (const float4*)(bbase + (kt));            \
    ra0 = ap[0]; ra1 = ap[1]; ra2 = ap[2]; ra3 = ap[3];          \
    rb0 = bp[0]; rb1 = bp[1]; rb2 = bp[2]; rb3 = bp[3]; }

#define WRITE_TILE(bb) {                                                       \
    bf16x8 p0, p1, q0v, q1v;                                                   \
    p0[0]=f2bs(ra0.x); p0[1]=f2bs(ra0.y); p0[2]=f2bs(ra0.z); p0[3]=f2bs(ra0.w);\
    p0[4]=f2bs(ra1.x); p0[5]=f2bs(ra1.y); p0[6]=f2bs(ra1.z); p0[7]=f2bs(ra1.w);\
    p1[0]=f2bs(ra2.x); p1[1]=f2bs(ra2.y); p1[2]=f2bs(ra2.z); p1[3]=f2bs(ra2.w);\
    p1[4]=f2bs(ra3.x); p1[5]=f2bs(ra3.y); p1[6]=f2bs(ra3.z); p1[7]=f2bs(ra3.w);\
    q0v[0]=f2bs(rb0.x); q0v[1]=f2bs(rb0.y); q0v[2]=f2bs(rb0.z); q0v[3]=f2bs(rb0.w);\
    q0v[4]=f2bs(rb1.x); q0v[5]=f2bs(rb1.y); q0v[6]=f2bs(rb1.z); q0v[7]=f2bs(rb1.w);\
    q1v[0]=f2bs(rb2.x); q1v[1]=f2bs(rb2.y); q1v[2]=f2bs(rb2.z); q1v[3]=f2bs(rb2.w);\
    q1v[4]=f2bs(rb3.x); q1v[5]=f2bs(rb3.y); q1v[6]=f2bs(rb3.z); q1v[7]=f2bs(rb3.w);\
    *(bf16x8*)&lA[bb][sr][kh]     = p0;  *(bf16x8*)&lA[bb][sr][kh + 8] = p1;   \
    *(bf16x8*)&lB[bb][sr][kh]     = q0v; *(bf16x8*)&lB[bb][sr][kh + 8] = q1v; }

#define COMPUTE(bb) {                                                              \
    bf16x8 af0 = *(const bf16x8*)&lA[bb][wr * 64 +  0 + lrow][kg * 8];             \
    bf16x8 af1 = *(const bf16x8*)&lA[bb][wr * 64 + 16 + lrow][kg * 8];             \
    bf16x8 af2 = *(const bf16x8*)&lA[bb][wr * 64 + 32 + lrow][kg * 8];             \
    bf16x8 af3 = *(const bf16x8*)&lA[bb][wr * 64 + 48 + lrow][kg * 8];             \
    bf16x8 bg0 = *(const bf16x8*)&lB[bb][wc * 64 +  0 + lrow][kg * 8];             \
    bf16x8 bg1 = *(const bf16x8*)&lB[bb][wc * 64 + 16 + lrow][kg * 8];             \
    bf16x8 bg2 = *(const bf16x8*)&lB[bb][wc * 64 + 32 + lrow][kg * 8];             \
    bf16x8 bg3 = *(const bf16x8*)&lB[bb][wc * 64 + 48 + lrow][kg * 8];             \
    acc[0][0] = __builtin_amdgcn_mfma_f32_16x16x32_bf16(af0, bg0, acc[0][0],0,0,0);\
    acc[0][1] = __builtin_amdgcn_mfma_f32_16x16x32_bf16(af0, bg1, acc[0][1],0,0,0);\
    acc[0][2] = __builtin_amdgcn_mfma_f32_16x16x32_bf16(af0, bg2, acc[0][2],0,0,0);\
    acc[0][3] = __builtin_amdgcn_mfma_f32_16x16x32_bf16(af0, bg3, acc[0][3],0,0,0);\
    acc[1][0] = __builtin_amdgcn_mfma_f32_16x16x32_bf16(af1, bg0, acc[1][0],0,0,0);\
    acc[1][1] = __builtin_amdgcn_mfma_f32_16x16x32_bf16(af1, bg1, acc[1][1],0,0,0);\
    acc[1][2] = __builtin_amdgcn_mfma_f32_16x16x32_bf16(af1, bg2, acc[1][2],0,0,0);\
    acc[1][3] = __builtin_amdgcn_mfma_f32_16x16x32_bf16(af1, bg3, acc[1][3],0,0,0);\
    acc[2][0] = __builtin_amdgcn_mfma_f32_16x16x32_bf16(af2, bg0, acc[2][0],0,0,0);\
    acc[2][1] = __builtin_amdgcn_mfma_f32_16x16x32_bf16(af2, bg1, acc[2][1],0,0,0);\
    acc[2][2] = __builtin_amdgcn_mfma_f32_16x16x32_bf16(af2, bg2, acc[2][2],0,0,0);\
    acc[2][3] = __builtin_amdgcn_mfma_f32_16x16x32_bf16(af2, bg3, acc[2][3],0,0,0);\
    acc[3][0] = __builtin_amdgcn_mfma_f32_16x16x32_bf16(af3, bg0, acc[3][0],0,0,0);\
    acc[3][1] = __builtin_amdgcn_mfma_f32_16x16x32_bf16(af3, bg1, acc[3][1],0,0,0);\
    acc[3][2] = __builtin_amdgcn_mfma_f32_16x16x32_bf16(af3, bg2, acc[3][2],0,0,0);\
    acc[3][3] = __builtin_amdgcn_mfma_f32_16x16x32_bf16(af3, bg3, acc[3][3],0,0,0); }

  LOAD_TILE(0);
  WRITE_TILE(0);
  __syncthreads();
  int buf = 0;
  for (int kt = 32; kt < D_DIM; kt += 32) {
    LOAD_TILE(kt);
    COMPUTE(buf);
    WRITE_TILE(buf ^ 1);
    __syncthreads();
    buf ^= 1;
  }
  COMPUTE(buf);
  unsigned* mbuf = (unsigned*)&lA[0][0][0];

  float c2v[4];
  bool  val[4];
  int   qloc[4];
#pragma unroll
  for (int nt = 0; nt < 4; nt++) {
    int ql = wc * 64 + nt * 16 + lrow;
    int q = q0 + ql;
    val[nt] = (q < QN);
    qloc[nt] = ql;
    c2v[nt] = c2[seg * QN + (val[nt] ? q : QN - 1)];
  }

#pragma unroll
  for (int mt = 0; mt < 4; mt++) {
#pragma unroll
    for (int r = 0; r < 4; r++) {
      int grow = m0 + wr * 64 + mt * 16 + kg * 4 + r;
      float x2r = x2[grow];
      if constexpr (MODE == 0) {
        float dmin = 1e30f;
#pragma unroll
        for (int nt = 0; nt < 4; nt++) {
          if (val[nt]) {
            float d = (x2r + c2v[nt]) - 2.0f * acc[mt][nt][r];
            dmin = fminf(dmin, d);
          }
        }
        dmin = fminf(dmin, __shfl_xor(dmin, 1, 64));
        dmin = fminf(dmin, __shfl_xor(dmin, 2, 64));
        dmin = fminf(dmin, __shfl_xor(dmin, 4, 64));
        dmin = fminf(dmin, __shfl_xor(dmin, 8, 64));
        if (lrow == 0)
          atomicMin(&minf[grow * NSEG + seg], __float_as_uint(fmaxf(dmin, 0.0f)));
      } else if constexpr (MODE == 1) {
        unsigned b1 = 0xFFFFFFFFu, b2 = 0xFFFFFFFFu;
#pragma unroll
        for (int nt = 0; nt < 4; nt++) {
          unsigned u = 0xFFFFFFFFu;
          if (val[nt]) {
            float d = (x2r + c2v[nt]) - 2.0f * acc[mt][nt][r];
            u = packkey(d, qloc[nt]);
          }
          if (u < b1) { b2 = b1; b1 = u; } else if (u < b2) b2 = u;
        }
#pragma unroll
        for (int m = 1; m < 16; m <<= 1) {
          unsigned o1 = shflx_u32(b1, m), o2 = shflx_u32(b2, m);
          unsigned n1 = min(b1, o1);
          unsigned n2 = min(max(b1, o1), min(b2, o2));
          b1 = n1; b2 = n2;
        }
        if (lrow == 0) {
          int rloc = wr * 64 + mt * 16 + kg * 4 + r;
          mbuf[(rloc * 2 + wc) * 2 + 0] = b1;
          mbuf[(rloc * 2 + wc) * 2 + 1] = b2;
        }
      } else {
        float dm = __uint_as_float(minf[grow * NSEG + seg]) + MARGIN_BF;
#pragma unroll
        for (int nt = 0; nt < 4; nt++) {
          if (val[nt]) {
            float d = (x2r + c2v[nt]) - 2.0f * acc[mt][nt][r];
            if (d <= dm) {
              unsigned idx = atomicAdd(cnt, 1u);
              if (idx < CAP)
                list[idx] = ((unsigned)grow << 15) | ((unsigned)seg << 12) |
                            (unsigned)(q0 + qloc[nt]);
            }
          }
        }
      }
    }
  }

  if constexpr (MODE == 1) {
    __syncthreads();
    if (tid < 128) {
      unsigned p1 = mbuf[(tid * 2 + 0) * 2 + 0];
      unsigned p2 = mbuf[(tid * 2 + 0) * 2 + 1];
      unsigned g1 = mbuf[(tid * 2 + 1) * 2 + 0];
      unsigned g2 = mbuf[(tid * 2 + 1) * 2 + 1];
      unsigned m1 = min(p1, g1);
      unsigned m2 = min(max(p1, g1), min(p2, g2));
      int grow = m0 + tid;
      size_t base = ((size_t)(grow * NSEG + seg) * 32 + blockIdx.y) * 2;
      stash[base + 0] = m1;
      stash[base + 1] = m2;
    }
  }
#undef LOAD_TILE
#undef WRITE_TILE
#undef COMPUTE
}

// ---------------- fused filter + exact fp32 rescore (one wave per cell) ----------------
__global__ __launch_bounds__(256) void filter_rescore_kernel(
    const float* __restrict__ x, const float* __restrict__ emb,
    const float* __restrict__ c2, const float* __restrict__ x2,
    const unsigned* __restrict__ stash, unsigned long long* __restrict__ cells,
    float margin) {
  int cell = blockIdx.x * 4 + (threadIdx.x >> 6);   // 32768 cells
  int lane = threadIdx.x & 63;
  int row = cell >> 3, seg = cell & 7;
  unsigned e = stash[(size_t)cell * 64 + lane];
  unsigned m = e;
  for (int msk = 1; msk < 64; msk <<= 1) m = min(m, shflx_u32(m, msk));
  float dcut = __uint_as_float(m & 0xFFFFFF80u) + margin;
  int myq = ((lane >> 1) << 7) + (int)(e & 127u);
  bool qual = (e != 0xFFFFFFFFu) &&
              (__uint_as_float(e & 0xFFFFFF80u) <= dcut) && (myq < QN);
  unsigned long long mask = __ballot(qual);
  unsigned long long best = 0ULL;
  const float4* xr = (const float4*)(x + (size_t)row * D_DIM);
  float x2r = x2[row];
  while (mask) {
    int L = __ffsll((long long)mask) - 1;
    mask &= mask - 1;
    int q = __shfl(myq, L, 64);
    const float4* cr = (const float4*)(emb + (size_t)(VOFF + seg * QN + q) * D_DIM);
    float s = 0.f;
#pragma unroll
    for (int j = 0; j < 4; j++) {
      float4 a = xr[j * 64 + lane];
      float4 b = cr[j * 64 + lane];
      s += a.x * b.x + a.y * b.y + a.z * b.z + a.w * b.w;
    }
    for (int msk2 = 1; msk2 < 64; msk2 <<= 1) s += __shfl_xor(s, msk2, 64);
    float dist = (x2r + c2[seg * QN + q]) - 2.0f * s;
    unsigned u = __float_as_uint(dist);
    unsigned asc = (u & 0x80000000u) ? ~u : (u | 0x80000000u);
    unsigned long long p = ((unsigned long long)(~asc) << 32) |
                           (unsigned long long)(~(unsigned)q);
    if (p > best) best = p;
  }
  if (lane == 0) cells[(size_t)row * NSEG + seg] = best;
}

// ---------------- list-based rescore (fallback path B only) ----------------
__global__ __launch_bounds__(256) void rescore_kernel(const float* __restrict__ x,
                                                      const float* __restrict__ emb,
                                                      const float* __restrict__ c2,
                                                      const float* __restrict__ x2,
                                                      const unsigned* __restrict__ list,
                                                      const unsigned* __restrict__ cnt,
                                                      unsigned long long* __restrict__ cells) {
  int nw = gridDim.x * 4;
  int wv = blockIdx.x * 4 + (threadIdx.x >> 6);
  int lane = threadIdx.x & 63;
  unsigned n = *cnt; if (n > CAP) n = CAP;
  for (unsigned i = wv; i < n; i += nw) {
    unsigned e = list[i];
    int row = e >> 15, seg = (e >> 12) & 7, q = e & 4095;
    const float4* xr = (const float4*)(x + (size_t)row * D_DIM);
    const float4* cr = (const float4*)(emb + (size_t)(VOFF + seg * QN + q) * D_DIM);
    float s = 0.f;
#pragma unroll
    for (int j = 0; j < 4; j++) {
      float4 a = xr[j * 64 + lane];
      float4 b = cr[j * 64 + lane];
      s += a.x * b.x + a.y * b.y + a.z * b.z + a.w * b.w;
    }
    for (int msk = 1; msk < 64; msk <<= 1) s += __shfl_xor(s, msk, 64);
    float dist = (x2[row] + c2[seg * QN + q]) - 2.0f * s;
    unsigned u = __float_as_uint(dist);
    unsigned asc = (u & 0x80000000u) ? ~u : (u | 0x80000000u);
    unsigned long long p = ((unsigned long long)(~asc) << 32) |
                           (unsigned long long)(~(unsigned)q);
    if (lane == 0) atomicMax(&cells[(size_t)row * NSEG + seg], p);
  }
}

// ---------------- gather + mse partial (fp32 emb) ----------------
__global__ __launch_bounds__(256) void gather_kernel(const float* __restrict__ x,
                                                     const float* __restrict__ emb,
                                                     const float* __restrict__ mask,
                                                     const unsigned long long* __restrict__ cells,
                                                     float* __restrict__ out,
                                                     double* __restrict__ part) {
  int n = blockIdx.x;
  int t = threadIdx.x;
  __shared__ int qsel[NSEG];
  if (t < NSEG) qsel[t] = (int)(~(unsigned)(cells[(size_t)n * NSEG + t] & 0xffffffffULL));
  __syncthreads();
  float4 xv = ((const float4*)(x + (size_t)n * D_DIM))[t];
  float ax = 0.f, ay = 0.f, az = 0.f, aw = 0.f;
#pragma unroll
  for (int s = 0; s < NSEG; s++) {
    float4 cv = ((const float4*)(emb + (size_t)(VOFF + s * QN + qsel[s]) * D_DIM))[t];
    ax += cv.x; ay += cv.y; az += cv.z; aw += cv.w;
  }
  float qx = ax * 0.125f, qy = ay * 0.125f, qz = az * 0.125f, qw = aw * 0.125f;
  float4 o4;
  o4.x = xv.x + (qx - xv.x);
  o4.y = xv.y + (qy - xv.y);
  o4.z = xv.z + (qz - xv.z);
  o4.w = xv.w + (qw - xv.w);
  ((float4*)(out + (size_t)n * D_DIM))[t] = o4;
  float mk = mask[n];
  float dx = qx * mk - xv.x * mk;
  float dy = qy * mk - xv.y * mk;
  float dz = qz * mk - xv.z * mk;
  float dw = qw * mk - xv.w * mk;
  float ss = dx * dx + dy * dy + dz * dz + dw * dw;
  double sd = (double)ss;
  for (int off = 32; off > 0; off >>= 1) sd += __shfl_down(sd, off, 64);
  __shared__ double red[4];
  if ((t & 63) == 0) red[t >> 6] = sd;
  __syncthreads();
  if (t == 0) part[n] = red[0] + red[1] + red[2] + red[3];
}

__global__ __launch_bounds__(256) void finalize_kernel(const double* __restrict__ part,
                                                       float* __restrict__ loss_out) {
  int t = threadIdx.x;
  double s = 0.0;
  for (int i = t; i < NROWS; i += 256) s += part[i];
  for (int off = 32; off > 0; off >>= 1) s += __shfl_down(s, off, 64);
  __shared__ double red[4];
  if ((t & 63) == 0) red[t >> 6] = s;
  __syncthreads();
  if (t == 0) {
    double tot = red[0] + red[1] + red[2] + red[3];
    float m = (float)(tot / (double)((size_t)NROWS * D_DIM));
    loss_out[0] = m + 0.25f * m;
  }
}

extern "C" void kernel_launch(void* const* d_in, const int* in_sizes, int n_in,
                              void* d_out, int out_size, void* d_ws, size_t ws_size,
                              hipStream_t stream) {
  const float* x    = (const float*)d_in[0];
  const float* emb  = (const float*)d_in[1];
  const float* mask = (const float*)d_in[2];
  (void)in_sizes; (void)n_in; (void)out_size;

  char* ws = (char*)d_ws;
  float* c2 = (float*)(ws + C2_OFF);
  float* x2 = (float*)(ws + X2_OFF);
  unsigned long long* cells = (unsigned long long*)(ws + CELLS_OFF);
  unsigned* minf = (unsigned*)(ws + MINF_OFF);
  unsigned* cnt  = (unsigned*)(ws + CNT_OFF);
  double*   part = (double*)(ws + PART_OFF);
  unsigned* list = (unsigned*)(ws + LIST_OFF);
  unsigned* stash = (unsigned*)(ws + STASH_OFF);
  char* xi8 = ws + XI8_OFF;
  char* ci8 = ws + CI8_OFF;
  float* sxs = (float*)(ws + SX_OFF);
  float* scs = (float*)(ws + SC_OFF);
  float* out = (float*)d_out;

  hipMemsetAsync(cells, 0, 262144, stream);
  hipMemsetAsync(cnt, 0, 256, stream);

  if (ws_size >= (size_t)WS_NEED_FAST) {
    convert_i8_kernel<<<dim3(NCODES + NROWS), 256, 0, stream>>>(emb, x, ci8, xi8, c2, x2, scs, sxs);
    score_i8_kernel<<<dim3(2048), 512, 0, stream>>>(xi8, ci8, c2, x2, scs, sxs, stash);
    filter_rescore_kernel<<<dim3(8192), 256, 0, stream>>>(x, emb, c2, x2, stash, cells, MARGIN_I8);
    gather_kernel<<<dim3(NROWS), 256, 0, stream>>>(x, emb, mask, cells, out, part);
  } else if (ws_size >= (size_t)WS_NEED_A) {
    rowsq_kernel<<<dim3(NCODES + NROWS), 256, 0, stream>>>(emb, x, c2, x2);
    score_mfma_kernel<1><<<dim3(NROWS / 128, (QN + 127) / 128, NSEG), 256, 0, stream>>>(
        x, emb, c2, x2, minf, stash, list, cnt);
    filter_rescore_kernel<<<dim3(8192), 256, 0, stream>>>(x, emb, c2, x2, stash, cells, MARGIN_BF);
    gather_kernel<<<dim3(NROWS), 256, 0, stream>>>(x, emb, mask, cells, out, part);
  } else {
    hipMemsetAsync(minf, 0xFF, 131072, stream);
    rowsq_kernel<<<dim3(NCODES + NROWS), 256, 0, stream>>>(emb, x, c2, x2);
    score_mfma_kernel<0><<<dim3(NROWS / 128, (QN + 127) / 128, NSEG), 256, 0, stream>>>(
        x, emb, c2, x2, minf, stash, list, cnt);
    score_mfma_kernel<2><<<dim3(NROWS / 128, (QN + 127) / 128, NSEG), 256, 0, stream>>>(
        x, emb, c2, x2, minf, stash, list, cnt);
    rescore_kernel<<<dim3(2048), 256, 0, stream>>>(x, emb, c2, x2, list, cnt, cells);
    gather_kernel<<<dim3(NROWS), 256, 0, stream>>>(x, emb, mask, cells, out, part);
  }
  finalize_kernel<<<dim3(1), 256, 0, stream>>>(part, out + (size_t)NROWS * D_DIM);
}